// Round 6
// baseline (92.014 us; speedup 1.0000x reference)
//
#include <hip/hip_runtime.h>

#define BB 8
#define CC 128
#define HH 64
#define WW 64
#define OO 128
#define KT 9
#define HWs (HH * WW)

typedef __attribute__((ext_vector_type(8))) _Float16 half8;
typedef __attribute__((ext_vector_type(8))) short short8;
typedef __attribute__((ext_vector_type(8))) unsigned short ushort8;
typedef __attribute__((ext_vector_type(4))) float f32x4;

__device__ inline unsigned short f2bf(float f) {
    union { float f; unsigned int u; } x; x.f = f;
    unsigned int u = x.u;
    unsigned int r = u + 0x7fff + ((u >> 16) & 1);
    return (unsigned short)(r >> 16);
}

// ---- prep 1: NCHW f32 -> NHWC f16 (proven) ----
__global__ __launch_bounds__(256) void prep_input(
    const float* __restrict__ in, _Float16* __restrict__ out) {
    __shared__ float t[CC][33];
    int b = blockIdx.y;
    int s0 = blockIdx.x * 32;
    int s = threadIdx.x & 31;
    int c0 = threadIdx.x >> 5;
    const float* ip = in + (size_t)b * CC * HWs;
#pragma unroll
    for (int c = 0; c < CC; c += 8)
        t[c + c0][s] = ip[(size_t)(c + c0) * HWs + s0 + s];
    __syncthreads();
    int ws = threadIdx.x >> 3;
    int cg = (threadIdx.x & 7) * 16;
    _Float16 v[16];
#pragma unroll
    for (int i = 0; i < 16; ++i) v[i] = (_Float16)t[cg + i][ws];
    _Float16* op = out + ((size_t)(b * HWs) + s0 + ws) * CC + cg;
    *(half8*)op = *(half8*)&v[0];
    *(half8*)(op + 8) = *(half8*)&v[8];
}

// ---- prep 2 (proven): weight (O,C,3,3) f32 -> wbf[k][o][c] bf16 ----
__global__ __launch_bounds__(256) void prep_weight(
    const float* __restrict__ w, unsigned short* __restrict__ wbf) {
    int i = blockIdx.x * 256 + threadIdx.x;
    if (i >= KT * OO * CC) return;
    int k = i / (OO * CC);
    int r = i % (OO * CC);
    int o = r >> 7, c = r & 127;
    wbf[i] = f2bf(w[o * (CC * KT) + c * KT + k]);
}

// ---- main ----
struct GatherR {
    half8 g[4];                 // 4 corners x 8 ch
    float w00, w01, w10, w11;
};

__device__ __forceinline__ void sample_issue(
    const _Float16* __restrict__ base, int ho, int wo, int cs, int k,
    float oy, float ox, float mm, GatherR& G) {
    int kh = k / 3, kw = k % 3;
    float py = (float)(ho - 1 + kh) + oy;
    float px = (float)(wo - 1 + kw) + ox;
    float fy = floorf(py), fx = floorf(px);
    float wy1 = py - fy, wx1 = px - fx;
    float wy0 = 1.f - wy1, wx0 = 1.f - wx1;
    int y0 = (int)fy, x0 = (int)fx;
    int y1 = y0 + 1, x1 = x0 + 1;
    bool vy0 = (y0 >= 0) & (y0 < HH);
    bool vy1 = (y1 >= 0) & (y1 < HH);
    bool vx0 = (x0 >= 0) & (x0 < WW);
    bool vx1 = (x1 >= 0) & (x1 < WW);
    G.w00 = (vy0 & vx0) ? wy0 * wx0 * mm : 0.f;
    G.w01 = (vy0 & vx1) ? wy0 * wx1 * mm : 0.f;
    G.w10 = (vy1 & vx0) ? wy1 * wx0 * mm : 0.f;
    G.w11 = (vy1 & vx1) ? wy1 * wx1 * mm : 0.f;
    int y0c = min(max(y0, 0), HH - 1), y1c = min(max(y1, 0), HH - 1);
    int x0c = min(max(x0, 0), WW - 1), x1c = min(max(x1, 0), WW - 1);
    G.g[0] = *(const half8*)(base + (size_t)(y0c * WW + x0c) * CC + cs);
    G.g[1] = *(const half8*)(base + (size_t)(y0c * WW + x1c) * CC + cs);
    G.g[2] = *(const half8*)(base + (size_t)(y1c * WW + x0c) * CC + cs);
    G.g[3] = *(const half8*)(base + (size_t)(y1c * WW + x1c) * CC + cs);
}

// f32 interp (proven numerics) -> one swizzled 16-B LDS store
__device__ __forceinline__ void interp_write(
    char* lbuf, int spx, int scs, const GatherR& G) {
    ushort8 o0;
#pragma unroll
    for (int j = 0; j < 8; ++j) {
        float s = G.w00 * (float)G.g[0][j] + G.w01 * (float)G.g[1][j] +
                  G.w10 * (float)G.g[2][j] + G.w11 * (float)G.g[3][j];
        o0[j] = f2bf(s);
    }
    unsigned addr = (unsigned)(spx * 256 + scs * 2);
    addr ^= (unsigned)((spx & 15) << 4);
    *(ushort8*)(lbuf + addr) = o0;
}

__global__ __launch_bounds__(256, 4) void deform_main(
    const _Float16* __restrict__ inh, const unsigned short* __restrict__ wbf,
    const float* __restrict__ offset, const float* __restrict__ mask,
    const float* __restrict__ bias, float* __restrict__ out) {
    __shared__ unsigned short Al[2][16 * 128];  // 2 x 4 KB, XOR(row&15) swizzle

    // 2048 blocks; XCD x owns batch image b = x (2 MB f16 in its 4 MB L2)
    int hw = blockIdx.x;
    int lb = (hw & 7) * 256 + (hw >> 3);
    int b = lb >> 8;
    int rem = lb & 255;
    int ho = rem >> 2;
    int px0 = (rem & 3) * 16;

    int tid = threadIdx.x;
    int wv = tid >> 6, l = tid & 63;
    int lr = l & 15, lg = l >> 4;

    // sampling role: 1 px x 8 ch per thread
    int spx = tid >> 4;           // 0..15
    int scs = (tid & 15) * 8;     // channel start
    int wo_s = px0 + spx;

    const _Float16* base = inh + (size_t)b * HWs * CC;
    const float* offp = offset + (size_t)b * 18 * HWs + ho * WW + wo_s;
    const float* mskp = mask + (size_t)b * 9 * HWs + ho * WW + wo_s;

    f32x4 acc[2] = {};
    GatherR G;
    short8 Bf[8];

    // compute role: wave's O-slice rows o = wv*32 + n*16 + lr
    int orow0 = (wv * 32 + lr) * CC + lg * 8;   // n=0 row offset in wk
    int orow1 = orow0 + 16 * CC;                // n=1

    // ---- prologue: tap 0 ----
    {
        float oy = offp[0], ox = offp[HWs], mm = mskp[0];
        sample_issue(base, ho, wo_s, scs, 0, oy, ox, mm, G);
    }
    float oyN = offp[2 * HWs], oxN = offp[3 * HWs], mmN = mskp[HWs];
    {
        const unsigned short* wk = wbf;  // tap 0
#pragma unroll
        for (int c = 0; c < 4; ++c) {
            Bf[c * 2 + 0] = *(const short8*)(wk + orow0 + c * 32);
            Bf[c * 2 + 1] = *(const short8*)(wk + orow1 + c * 32);
        }
    }
    interp_write((char*)Al[0], spx, scs, G);
    sample_issue(base, ho, wo_s, scs, 1, oyN, oxN, mmN, G);
    oyN = offp[4 * HWs]; oxN = offp[5 * HWs]; mmN = mskp[2 * HWs];
    __syncthreads();

    for (int k = 0; k < KT; ++k) {
        // (1) MFMA(k): A-frags from LDS (conflict-free swizzle), B from regs
#pragma unroll
        for (int c = 0; c < 4; ++c) {
            unsigned addr = (unsigned)(lr * 256 + c * 64 + lg * 16);
            addr ^= (unsigned)(lr << 4);
            short8 af = *(const short8*)((const char*)Al[k & 1] + addr);
            acc[0] = __builtin_amdgcn_mfma_f32_16x16x32_bf16(af, Bf[c * 2 + 0], acc[0], 0, 0, 0);
            acc[1] = __builtin_amdgcn_mfma_f32_16x16x32_bf16(af, Bf[c * 2 + 1], acc[1], 0, 0, 0);
        }

        if (k < KT - 1) {
            // (2) B-frags for tap k+1 (L1/L2-hot)
            const unsigned short* wk = wbf + (size_t)(k + 1) * OO * CC;
#pragma unroll
            for (int c = 0; c < 4; ++c) {
                Bf[c * 2 + 0] = *(const short8*)(wk + orow0 + c * 32);
                Bf[c * 2 + 1] = *(const short8*)(wk + orow1 + c * 32);
            }
            // (3) interp(k+1) — gathers issued one full iteration ago
            interp_write((char*)Al[(k + 1) & 1], spx, scs, G);
            // (4) issue gathers(k+2) + prefetch offsets(k+3)
            if (k < KT - 2) {
                sample_issue(base, ho, wo_s, scs, k + 2, oyN, oxN, mmN, G);
                if (k < KT - 3) {
                    oyN = offp[(2 * k + 6) * HWs];
                    oxN = offp[(2 * k + 7) * HWs];
                    mmN = mskp[(k + 3) * HWs];
                }
            }
            __syncthreads();
        }
    }

    // ---- epilogue ----
#pragma unroll
    for (int n = 0; n < 2; ++n) {
        int o = wv * 32 + n * 16 + lr;
        float bs = bias[o];
        float4 v;
        v.x = acc[n][0] + bs;
        v.y = acc[n][1] + bs;
        v.z = acc[n][2] + bs;
        v.w = acc[n][3] + bs;
        int wo0 = px0 + lg * 4;
        *(float4*)(out + (size_t)(b * OO + o) * HWs + ho * WW + wo0) = v;
    }
}

extern "C" void kernel_launch(void* const* d_in, const int* in_sizes, int n_in,
                              void* d_out, int out_size, void* d_ws, size_t ws_size,
                              hipStream_t stream) {
    const float* inp    = (const float*)d_in[0];
    const float* offset = (const float*)d_in[1];
    const float* mask   = (const float*)d_in[2];
    const float* weight = (const float*)d_in[3];
    const float* bias   = (const float*)d_in[4];
    float* out = (float*)d_out;

    _Float16* inh = (_Float16*)d_ws;  // 8 MB
    unsigned short* wbf =
        (unsigned short*)((char*)d_ws + (size_t)BB * HWs * CC * sizeof(_Float16));

    prep_input<<<dim3(128, 8), 256, 0, stream>>>(inp, inh);
    prep_weight<<<dim3((KT * OO * CC + 255) / 256), 256, 0, stream>>>(weight, wbf);
    deform_main<<<dim3(2048), 256, 0, stream>>>(inh, wbf, offset, mask, bias, out);
}